// Round 5
// baseline (591.794 us; speedup 1.0000x reference)
//
#include <hip/hip_runtime.h>
#include <stdint.h>

#define GN 8192
#define LOG2E 1.4426950408889634f

typedef float f32x4 __attribute__((ext_vector_type(4)));
typedef short s16x8 __attribute__((ext_vector_type(8)));
typedef unsigned short u16x8 __attribute__((ext_vector_type(8)));
typedef int i32x4 __attribute__((ext_vector_type(4)));

__device__ __forceinline__ unsigned short f2bf(float f) {
    unsigned int u = __float_as_uint(f);
    u += 0x7FFFu + ((u >> 16) & 1u);
    return (unsigned short)(u >> 16);
}
__device__ __forceinline__ float bf2f(unsigned short h) {
    return __uint_as_float(((unsigned int)h) << 16);
}

// w1[k] = log2e * sum_o W[k][o]*a[o];  w2 likewise (pre-scaled for exp2).
__global__ void kA(const float* __restrict__ W, const float* __restrict__ a,
                   float* __restrict__ w1, float* __restrict__ w2) {
    int k = blockIdx.x, l = threadIdx.x;
    float s1 = 0.f, s2 = 0.f;
#pragma unroll
    for (int q = 0; q < 4; ++q) {
        int o = l + q * 64;
        float w = W[k * 256 + o];
        s1 += w * a[o];
        s2 += w * a[256 + o];
    }
#pragma unroll
    for (int off = 32; off; off >>= 1) {
        s1 += __shfl_xor(s1, off);
        s2 += __shfl_xor(s2, off);
    }
    if (l == 0) {
        w1[k] = s1 * LOG2E;
        w2[k] = s2 * LOG2E;
    }
}

// wtT[o][k] = bf16(wtrans[k][o]) via LDS 32x32 tile transpose (coalesced both sides).
__global__ __launch_bounds__(256) void kA2(const float* __restrict__ wt,
                                           unsigned short* __restrict__ wtT) {
    __shared__ unsigned short Tt[32][33];
    const int bi = blockIdx.x;   // 8 tiles along o (256)
    const int bj = blockIdx.y;   // 16 tiles along k (512)
    const int ty = threadIdx.x >> 3, tx8 = threadIdx.x & 7;
    float4 v = *(const float4*)(wt + (size_t)(bj * 32 + ty) * 256 + bi * 32 + tx8 * 4);
    Tt[tx8 * 4 + 0][ty] = f2bf(v.x);
    Tt[tx8 * 4 + 1][ty] = f2bf(v.y);
    Tt[tx8 * 4 + 2][ty] = f2bf(v.z);
    Tt[tx8 * 4 + 3][ty] = f2bf(v.w);
    __syncthreads();
    ushort4 o4;
    o4.x = Tt[ty][tx8 * 4 + 0];
    o4.y = Tt[ty][tx8 * 4 + 1];
    o4.z = Tt[ty][tx8 * 4 + 2];
    o4.w = Tt[ty][tx8 * 4 + 3];
    *(ushort4*)(wtT + (size_t)(bi * 32 + ty) * 512 + bj * 32 + tx8 * 4) = o4;
}

// s = inp@w1, t = inp@w2 (pre-scaled), inpT[c][r] = bf16(inp[r][c])
__global__ __launch_bounds__(256) void kB(const float* __restrict__ inp,
                                          const float* __restrict__ w1,
                                          const float* __restrict__ w2,
                                          float* __restrict__ s, float* __restrict__ t,
                                          unsigned short* __restrict__ inpT) {
    __shared__ unsigned short T[256][33];
    const int tid = threadIdx.x;
    const int r0 = blockIdx.x * 32;
    const int r = tid >> 3, cs = tid & 7;
    const float4* in4 = (const float4*)(inp + (size_t)(r0 + r) * 256 + cs * 32);
    const float4* w14 = (const float4*)(w1 + cs * 32);
    const float4* w24 = (const float4*)(w2 + cs * 32);
    float zs = 0.f, zt = 0.f;
#pragma unroll
    for (int q = 0; q < 8; ++q) {
        float4 v = in4[q];
        float4 a1 = w14[q];
        float4 a2 = w24[q];
        zs += v.x * a1.x + v.y * a1.y + v.z * a1.z + v.w * a1.w;
        zt += v.x * a2.x + v.y * a2.y + v.z * a2.z + v.w * a2.w;
        int c = cs * 32 + q * 4;
        T[c + 0][r] = f2bf(v.x);
        T[c + 1][r] = f2bf(v.y);
        T[c + 2][r] = f2bf(v.z);
        T[c + 3][r] = f2bf(v.w);
    }
#pragma unroll
    for (int off = 1; off < 8; off <<= 1) {
        zs += __shfl_xor(zs, off);
        zt += __shfl_xor(zt, off);
    }
    if (cs == 0) {
        s[r0 + r] = zs;
        t[r0 + r] = zt;
    }
    __syncthreads();
    unsigned short* dst = inpT + (size_t)tid * GN + r0;
    ushort4* d4 = (ushort4*)dst;
#pragma unroll
    for (int q = 0; q < 8; ++q) {
        ushort4 v;
        v.x = T[tid][q * 4 + 0];
        v.y = T[tid][q * 4 + 1];
        v.z = T[tid][q * 4 + 2];
        v.w = T[tid][q * 4 + 3];
        d4[q] = v;
    }
}

#define PROC(AM, TX, BP, BN)                   \
    {                                          \
        float e = sr + (TX);                   \
        float l = fmaxf(e, 0.2f * e);          \
        float p1 = (AM) ? exp2f(l) : 0.f;      \
        float p2 = (AM) ? exp2f(-l) : 0.f;     \
        unsigned short b1 = f2bf(p1);          \
        unsigned short b2 = f2bf(p2);          \
        zp += bf2f(b1);                        \
        zn += bf2f(b2);                        \
        BP = b1;                               \
        BN = b2;                               \
    }

// Fully fused: masked double-softmax attention + output GEMM + elu.
// Block: 16 rows x 8192 cols, 512 threads / 8 waves, grid 512 (2 blocks/CU).
__global__ __launch_bounds__(512, 4) void kC(const int* __restrict__ adj,
                                             const float* __restrict__ sv,
                                             const float* __restrict__ tv,
                                             const unsigned short* __restrict__ inpT,
                                             const unsigned short* __restrict__ wtT,
                                             float* __restrict__ out) {
    __shared__ __align__(16) char smem[16384];  // ptP[0:8K) ptN[8K:16K); hdl overlays all 16K
    __shared__ float Zs[32];
    char* ldsP = smem;
    char* ldsN = smem + 8192;
    const int tid = threadIdx.x;
    const int lane = tid & 63, w = tid >> 6;
    const int rr = lane & 15, hi = lane >> 4;
    const int r = tid >> 5, c8 = tid & 31;  // exp role: row r, cols c8*8..+8
    const int i0 = blockIdx.x * 16;
    const float sr = sv[i0 + r];
    float zp = 0.f, zn = 0.f;
    f32x4 accP[2], accN[2];
    accP[0] = (f32x4)(0.f);
    accP[1] = (f32x4)(0.f);
    accN[0] = (f32x4)(0.f);
    accN[1] = (f32x4)(0.f);
    const int fb = w * 32;  // this wave's 32-feature slice
    const int wb = (r * 512 + c8 * 16) ^ ((r & 7) << 4);
    const size_t arow = (size_t)(i0 + r) * GN + c8 * 8;
    const float* tb = tv + c8 * 8;

    // prologue: prefetch chunk 0 adjacency + t
    i32x4 ca0 = __builtin_nontemporal_load((const i32x4*)(adj + arow));
    i32x4 ca1 = __builtin_nontemporal_load((const i32x4*)(adj + arow + 4));
    float4 tf0 = *(const float4*)(tb);
    float4 tf1 = *(const float4*)(tb + 4);

    for (int jc = 0; jc < 32; ++jc) {
        // this chunk's B fragments (L2-resident inpT) -> registers
        s16x8 bvr[16];
        const unsigned short* bcol = inpT + jc * 256 + hi * 8;
#pragma unroll
        for (int kc = 0; kc < 8; ++kc) {
            bvr[kc * 2 + 0] = *(const s16x8*)(bcol + (size_t)(fb + rr) * GN + kc * 32);
            bvr[kc * 2 + 1] = *(const s16x8*)(bcol + (size_t)(fb + 16 + rr) * GN + kc * 32);
        }
        // exp phase on prefetched adj/t
        u16x8 up, un;
        PROC(ca0.x, tf0.x, up[0], un[0]);
        PROC(ca0.y, tf0.y, up[1], un[1]);
        PROC(ca0.z, tf0.z, up[2], un[2]);
        PROC(ca0.w, tf0.w, up[3], un[3]);
        PROC(ca1.x, tf1.x, up[4], un[4]);
        PROC(ca1.y, tf1.y, up[5], un[5]);
        PROC(ca1.z, tf1.z, up[6], un[6]);
        PROC(ca1.w, tf1.w, up[7], un[7]);
        // prefetch next chunk (stays in flight across the raw barriers)
        if (jc < 31) {
            const int* an = adj + arow + (jc + 1) * 256;
            ca0 = __builtin_nontemporal_load((const i32x4*)(an));
            ca1 = __builtin_nontemporal_load((const i32x4*)(an + 4));
            const float* tn = tb + (jc + 1) * 256;
            tf0 = *(const float4*)(tn);
            tf1 = *(const float4*)(tn + 4);
        }
        // barrier 1: previous MFMA phase's LDS reads complete before overwrite
        asm volatile("" ::: "memory");
        __builtin_amdgcn_s_barrier();
        asm volatile("" ::: "memory");
        *(u16x8*)(ldsP + wb) = up;
        *(u16x8*)(ldsN + wb) = un;
        // barrier 2: LDS writes visible; do NOT drain vmcnt (prefetches in flight)
        asm volatile("s_waitcnt lgkmcnt(0)" ::: "memory");
        __builtin_amdgcn_s_barrier();
        asm volatile("" ::: "memory");
        // MFMA phase: LDS A-frags + register B
#pragma unroll
        for (int kc = 0; kc < 8; ++kc) {
            int rb = (rr * 512 + kc * 64 + hi * 16) ^ ((rr & 7) << 4);
            s16x8 aP = *(const s16x8*)(ldsP + rb);
            s16x8 aN = *(const s16x8*)(ldsN + rb);
            accP[0] = __builtin_amdgcn_mfma_f32_16x16x32_bf16(aP, bvr[kc * 2 + 0], accP[0], 0, 0, 0);
            accP[1] = __builtin_amdgcn_mfma_f32_16x16x32_bf16(aP, bvr[kc * 2 + 1], accP[1], 0, 0, 0);
            accN[0] = __builtin_amdgcn_mfma_f32_16x16x32_bf16(aN, bvr[kc * 2 + 0], accN[0], 0, 0, 0);
            accN[1] = __builtin_amdgcn_mfma_f32_16x16x32_bf16(aN, bvr[kc * 2 + 1], accN[1], 0, 0, 0);
        }
    }
    // Z reduce across the 32 lanes sharing row r (lanes 0-31 / 32-63 halves)
#pragma unroll
    for (int off = 1; off < 32; off <<= 1) {
        zp += __shfl_xor(zp, off);
        zn += __shfl_xor(zn, off);
    }
    if ((tid & 31) == 0) {
        Zs[r] = zp;
        Zs[16 + r] = zn;
    }
    __syncthreads();  // also: all MFMA-phase LDS reads done -> hdl may overlay
    // hd tile -> LDS (bf16, swizzled): hd = [num+/Z+, -num-/Z-], [16][512]
    char* hdl = smem;
#pragma unroll
    for (int reg = 0; reg < 4; ++reg) {
        int row = hi * 4 + reg;
        float izp = 1.f / Zs[row];
        float izn = 1.f / Zs[16 + row];
        int sw = (row & 7) << 4;
#pragma unroll
        for (int nt = 0; nt < 2; ++nt) {
            int col = fb + nt * 16 + rr;
            *(unsigned short*)(hdl + ((row * 1024 + col * 2) ^ sw)) =
                f2bf(accP[nt][reg] * izp);
            *(unsigned short*)(hdl + ((row * 1024 + (col + 256) * 2) ^ sw)) =
                f2bf(-accN[nt][reg] * izn);
        }
    }
    __syncthreads();
    // output GEMM: out[16][256] = elu(hdl[16][512] @ wtT^T); wave w -> cols w*32..+31
    f32x4 oc[2];
    oc[0] = (f32x4)(0.f);
    oc[1] = (f32x4)(0.f);
#pragma unroll
    for (int kc = 0; kc < 16; ++kc) {
        int rb = (rr * 1024 + kc * 64 + hi * 16) ^ ((rr & 7) << 4);
        s16x8 av = *(const s16x8*)(hdl + rb);
#pragma unroll
        for (int nt = 0; nt < 2; ++nt) {
            s16x8 b = *(const s16x8*)(wtT + (size_t)(fb + nt * 16 + rr) * 512 + kc * 32 + hi * 8);
            oc[nt] = __builtin_amdgcn_mfma_f32_16x16x32_bf16(av, b, oc[nt], 0, 0, 0);
        }
    }
#pragma unroll
    for (int nt = 0; nt < 2; ++nt) {
        int col = fb + nt * 16 + rr;
#pragma unroll
        for (int reg = 0; reg < 4; ++reg) {
            int row = i0 + hi * 4 + reg;
            float x = oc[nt][reg];
            out[(size_t)row * 256 + col] = x > 0.f ? x : __expf(x) - 1.f;
        }
    }
}

extern "C" void kernel_launch(void* const* d_in, const int* in_sizes, int n_in,
                              void* d_out, int out_size, void* d_ws, size_t ws_size,
                              hipStream_t stream) {
    const float* inp = (const float*)d_in[0];
    const int* adj = (const int*)d_in[1];
    const float* W = (const float*)d_in[2];
    const float* a = (const float*)d_in[3];
    const float* wt = (const float*)d_in[4];
    float* out = (float*)d_out;
    char* ws = (char*)d_ws;

    unsigned short* inpT = (unsigned short*)ws;                 // 4 MB  [256][8192] bf16
    float* s = (float*)(ws + (4 << 20));                        // 32 KB
    float* t = (float*)(ws + (4 << 20) + (1 << 15));            // 32 KB
    float* w1 = (float*)(ws + (4 << 20) + (2 << 15));           // 1 KB
    float* w2 = (float*)(ws + (4 << 20) + (2 << 15) + 4096);    // 1 KB
    unsigned short* wtT = (unsigned short*)(ws + (4 << 20) + (2 << 15) + 8192);  // 256 KB

    hipLaunchKernelGGL(kA, dim3(256), dim3(64), 0, stream, W, a, w1, w2);
    hipLaunchKernelGGL(kA2, dim3(8, 16), dim3(256), 0, stream, wt, wtT);
    hipLaunchKernelGGL(kB, dim3(256), dim3(256), 0, stream, inp, w1, w2, s, t, inpT);
    hipLaunchKernelGGL(kC, dim3(512), dim3(512), 0, stream, adj, s, t, inpT, wtT, out);
}

// Round 6
// 581.052 us; speedup vs baseline: 1.0185x; 1.0185x over previous
//
#include <hip/hip_runtime.h>
#include <stdint.h>

#define GN 8192
#define LOG2E 1.4426950408889634f

typedef float f32x4 __attribute__((ext_vector_type(4)));
typedef short s16x8 __attribute__((ext_vector_type(8)));
typedef unsigned short u16x8 __attribute__((ext_vector_type(8)));
typedef int i32x4 __attribute__((ext_vector_type(4)));

__device__ __forceinline__ unsigned short f2bf(float f) {
    unsigned int u = __float_as_uint(f);
    u += 0x7FFFu + ((u >> 16) & 1u);
    return (unsigned short)(u >> 16);
}
__device__ __forceinline__ float bf2f(unsigned short h) {
    return __uint_as_float(((unsigned int)h) << 16);
}

// w1[k] = log2e * sum_o W[k][o]*a[o];  w2 likewise (pre-scaled for exp2).
__global__ void kA(const float* __restrict__ W, const float* __restrict__ a,
                   float* __restrict__ w1, float* __restrict__ w2) {
    int k = blockIdx.x, l = threadIdx.x;
    float s1 = 0.f, s2 = 0.f;
#pragma unroll
    for (int q = 0; q < 4; ++q) {
        int o = l + q * 64;
        float w = W[k * 256 + o];
        s1 += w * a[o];
        s2 += w * a[256 + o];
    }
#pragma unroll
    for (int off = 32; off; off >>= 1) {
        s1 += __shfl_xor(s1, off);
        s2 += __shfl_xor(s2, off);
    }
    if (l == 0) {
        w1[k] = s1 * LOG2E;
        w2[k] = s2 * LOG2E;
    }
}

// wtT[o][k] = bf16(wtrans[k][o]) via LDS 32x32 tile transpose (coalesced both sides).
__global__ __launch_bounds__(256) void kA2(const float* __restrict__ wt,
                                           unsigned short* __restrict__ wtT) {
    __shared__ unsigned short Tt[32][33];
    const int bi = blockIdx.x;   // 8 tiles along o (256)
    const int bj = blockIdx.y;   // 16 tiles along k (512)
    const int ty = threadIdx.x >> 3, tx8 = threadIdx.x & 7;
    float4 v = *(const float4*)(wt + (size_t)(bj * 32 + ty) * 256 + bi * 32 + tx8 * 4);
    Tt[tx8 * 4 + 0][ty] = f2bf(v.x);
    Tt[tx8 * 4 + 1][ty] = f2bf(v.y);
    Tt[tx8 * 4 + 2][ty] = f2bf(v.z);
    Tt[tx8 * 4 + 3][ty] = f2bf(v.w);
    __syncthreads();
    ushort4 o4;
    o4.x = Tt[ty][tx8 * 4 + 0];
    o4.y = Tt[ty][tx8 * 4 + 1];
    o4.z = Tt[ty][tx8 * 4 + 2];
    o4.w = Tt[ty][tx8 * 4 + 3];
    *(ushort4*)(wtT + (size_t)(bi * 32 + ty) * 512 + bj * 32 + tx8 * 4) = o4;
}

// s = inp@w1, t = inp@w2 (pre-scaled), inpT[c][r] = bf16(inp[r][c])
__global__ __launch_bounds__(256) void kB(const float* __restrict__ inp,
                                          const float* __restrict__ w1,
                                          const float* __restrict__ w2,
                                          float* __restrict__ s, float* __restrict__ t,
                                          unsigned short* __restrict__ inpT) {
    __shared__ unsigned short T[256][33];
    const int tid = threadIdx.x;
    const int r0 = blockIdx.x * 32;
    const int r = tid >> 3, cs = tid & 7;
    const float4* in4 = (const float4*)(inp + (size_t)(r0 + r) * 256 + cs * 32);
    const float4* w14 = (const float4*)(w1 + cs * 32);
    const float4* w24 = (const float4*)(w2 + cs * 32);
    float zs = 0.f, zt = 0.f;
#pragma unroll
    for (int q = 0; q < 8; ++q) {
        float4 v = in4[q];
        float4 a1 = w14[q];
        float4 a2 = w24[q];
        zs += v.x * a1.x + v.y * a1.y + v.z * a1.z + v.w * a1.w;
        zt += v.x * a2.x + v.y * a2.y + v.z * a2.z + v.w * a2.w;
        int c = cs * 32 + q * 4;
        T[c + 0][r] = f2bf(v.x);
        T[c + 1][r] = f2bf(v.y);
        T[c + 2][r] = f2bf(v.z);
        T[c + 3][r] = f2bf(v.w);
    }
#pragma unroll
    for (int off = 1; off < 8; off <<= 1) {
        zs += __shfl_xor(zs, off);
        zt += __shfl_xor(zt, off);
    }
    if (cs == 0) {
        s[r0 + r] = zs;
        t[r0 + r] = zt;
    }
    __syncthreads();
    unsigned short* dst = inpT + (size_t)tid * GN + r0;
    ushort4* d4 = (ushort4*)dst;
#pragma unroll
    for (int q = 0; q < 8; ++q) {
        ushort4 v;
        v.x = T[tid][q * 4 + 0];
        v.y = T[tid][q * 4 + 1];
        v.z = T[tid][q * 4 + 2];
        v.w = T[tid][q * 4 + 3];
        d4[q] = v;
    }
}

#define PROC(AM, TX, BP, BN)                   \
    {                                          \
        float e = sr + (TX);                   \
        float l = fmaxf(e, 0.2f * e);          \
        float p1 = (AM) ? exp2f(l) : 0.f;      \
        float p2 = (AM) ? exp2f(-l) : 0.f;     \
        unsigned short b1 = f2bf(p1);          \
        unsigned short b2 = f2bf(p2);          \
        zp += bf2f(b1);                        \
        zn += bf2f(b2);                        \
        BP = b1;                               \
        BN = b2;                               \
    }

// Fully fused: masked double-softmax attention + output GEMM + elu.
// Block: 16 rows x 8192 cols, 512 threads / 8 waves, grid 512.
// launch_bounds(512,2): VGPR cap 128 -> compiler ~112 (R3) -> HW fits 2 blocks/CU.
__global__ __launch_bounds__(512, 2) void kC(const int* __restrict__ adj,
                                             const float* __restrict__ sv,
                                             const float* __restrict__ tv,
                                             const unsigned short* __restrict__ inpT,
                                             const unsigned short* __restrict__ wtT,
                                             float* __restrict__ out) {
    __shared__ __align__(16) char smem[16384];  // ptP[0:8K) ptN[8K:16K); hdl overlays all 16K
    __shared__ float Zs[32];
    char* ldsP = smem;
    char* ldsN = smem + 8192;
    const int tid = threadIdx.x;
    const int lane = tid & 63, w = tid >> 6;
    const int rr = lane & 15, hi = lane >> 4;
    const int r = tid >> 5, c8 = tid & 31;  // exp role: row r, cols c8*8..+8
    const int i0 = blockIdx.x * 16;
    const float sr = sv[i0 + r];
    float zp = 0.f, zn = 0.f;
    f32x4 accP[2], accN[2];
    accP[0] = (f32x4)(0.f);
    accP[1] = (f32x4)(0.f);
    accN[0] = (f32x4)(0.f);
    accN[1] = (f32x4)(0.f);
    const int fb = w * 32;  // this wave's 32-feature slice
    const int wb = (r * 512 + c8 * 16) ^ ((r & 7) << 4);
    const size_t arow = (size_t)(i0 + r) * GN + c8 * 8;
    const float* tb = tv + c8 * 8;

    // prologue: prefetch chunk 0 adjacency + t
    i32x4 ca0 = __builtin_nontemporal_load((const i32x4*)(adj + arow));
    i32x4 ca1 = __builtin_nontemporal_load((const i32x4*)(adj + arow + 4));
    float4 tf0 = *(const float4*)(tb);
    float4 tf1 = *(const float4*)(tb + 4);

    for (int jc = 0; jc < 32; ++jc) {
        // this chunk's B fragments (L2-resident inpT) -> registers
        s16x8 bvr[16];
        const unsigned short* bcol = inpT + jc * 256 + hi * 8;
#pragma unroll
        for (int kc = 0; kc < 8; ++kc) {
            bvr[kc * 2 + 0] = *(const s16x8*)(bcol + (size_t)(fb + rr) * GN + kc * 32);
            bvr[kc * 2 + 1] = *(const s16x8*)(bcol + (size_t)(fb + 16 + rr) * GN + kc * 32);
        }
        // exp phase on prefetched adj/t
        u16x8 up, un;
        PROC(ca0.x, tf0.x, up[0], un[0]);
        PROC(ca0.y, tf0.y, up[1], un[1]);
        PROC(ca0.z, tf0.z, up[2], un[2]);
        PROC(ca0.w, tf0.w, up[3], un[3]);
        PROC(ca1.x, tf1.x, up[4], un[4]);
        PROC(ca1.y, tf1.y, up[5], un[5]);
        PROC(ca1.z, tf1.z, up[6], un[6]);
        PROC(ca1.w, tf1.w, up[7], un[7]);
        // prefetch next chunk (stays in flight across the raw barriers)
        if (jc < 31) {
            const int* an = adj + arow + (jc + 1) * 256;
            ca0 = __builtin_nontemporal_load((const i32x4*)(an));
            ca1 = __builtin_nontemporal_load((const i32x4*)(an + 4));
            const float* tn = tb + (jc + 1) * 256;
            tf0 = *(const float4*)(tn);
            tf1 = *(const float4*)(tn + 4);
        }
        // barrier 1: previous MFMA phase's LDS reads complete before overwrite
        asm volatile("" ::: "memory");
        __builtin_amdgcn_s_barrier();
        asm volatile("" ::: "memory");
        *(u16x8*)(ldsP + wb) = up;
        *(u16x8*)(ldsN + wb) = un;
        // barrier 2: LDS writes visible; do NOT drain vmcnt (prefetches in flight)
        asm volatile("s_waitcnt lgkmcnt(0)" ::: "memory");
        __builtin_amdgcn_s_barrier();
        asm volatile("" ::: "memory");
        // MFMA phase: LDS A-frags + register B
#pragma unroll
        for (int kc = 0; kc < 8; ++kc) {
            int rb = (rr * 512 + kc * 64 + hi * 16) ^ ((rr & 7) << 4);
            s16x8 aP = *(const s16x8*)(ldsP + rb);
            s16x8 aN = *(const s16x8*)(ldsN + rb);
            accP[0] = __builtin_amdgcn_mfma_f32_16x16x32_bf16(aP, bvr[kc * 2 + 0], accP[0], 0, 0, 0);
            accP[1] = __builtin_amdgcn_mfma_f32_16x16x32_bf16(aP, bvr[kc * 2 + 1], accP[1], 0, 0, 0);
            accN[0] = __builtin_amdgcn_mfma_f32_16x16x32_bf16(aN, bvr[kc * 2 + 0], accN[0], 0, 0, 0);
            accN[1] = __builtin_amdgcn_mfma_f32_16x16x32_bf16(aN, bvr[kc * 2 + 1], accN[1], 0, 0, 0);
        }
    }
    // Z reduce across the 32 lanes sharing row r (lanes 0-31 / 32-63 halves)
#pragma unroll
    for (int off = 1; off < 32; off <<= 1) {
        zp += __shfl_xor(zp, off);
        zn += __shfl_xor(zn, off);
    }
    if ((tid & 31) == 0) {
        Zs[r] = zp;
        Zs[16 + r] = zn;
    }
    __syncthreads();  // also: all MFMA-phase LDS reads done -> hdl may overlay
    // hd tile -> LDS (bf16, swizzled): hd = [num+/Z+, -num-/Z-], [16][512]
    char* hdl = smem;
#pragma unroll
    for (int reg = 0; reg < 4; ++reg) {
        int row = hi * 4 + reg;
        float izp = 1.f / Zs[row];
        float izn = 1.f / Zs[16 + row];
        int sw = (row & 7) << 4;
#pragma unroll
        for (int nt = 0; nt < 2; ++nt) {
            int col = fb + nt * 16 + rr;
            *(unsigned short*)(hdl + ((row * 1024 + col * 2) ^ sw)) =
                f2bf(accP[nt][reg] * izp);
            *(unsigned short*)(hdl + ((row * 1024 + (col + 256) * 2) ^ sw)) =
                f2bf(-accN[nt][reg] * izn);
        }
    }
    __syncthreads();
    // output GEMM: out[16][256] = elu(hdl[16][512] @ wtT^T); wave w -> cols w*32..+31
    f32x4 oc[2];
    oc[0] = (f32x4)(0.f);
    oc[1] = (f32x4)(0.f);
#pragma unroll
    for (int kc = 0; kc < 16; ++kc) {
        int rb = (rr * 1024 + kc * 64 + hi * 16) ^ ((rr & 7) << 4);
        s16x8 av = *(const s16x8*)(hdl + rb);
#pragma unroll
        for (int nt = 0; nt < 2; ++nt) {
            s16x8 b = *(const s16x8*)(wtT + (size_t)(fb + nt * 16 + rr) * 512 + kc * 32 + hi * 8);
            oc[nt] = __builtin_amdgcn_mfma_f32_16x16x32_bf16(av, b, oc[nt], 0, 0, 0);
        }
    }
#pragma unroll
    for (int nt = 0; nt < 2; ++nt) {
        int col = fb + nt * 16 + rr;
#pragma unroll
        for (int reg = 0; reg < 4; ++reg) {
            int row = i0 + hi * 4 + reg;
            float x = oc[nt][reg];
            out[(size_t)row * 256 + col] = x > 0.f ? x : __expf(x) - 1.f;
        }
    }
}

extern "C" void kernel_launch(void* const* d_in, const int* in_sizes, int n_in,
                              void* d_out, int out_size, void* d_ws, size_t ws_size,
                              hipStream_t stream) {
    const float* inp = (const float*)d_in[0];
    const int* adj = (const int*)d_in[1];
    const float* W = (const float*)d_in[2];
    const float* a = (const float*)d_in[3];
    const float* wt = (const float*)d_in[4];
    float* out = (float*)d_out;
    char* ws = (char*)d_ws;

    unsigned short* inpT = (unsigned short*)ws;                 // 4 MB  [256][8192] bf16
    float* s = (float*)(ws + (4 << 20));                        // 32 KB
    float* t = (float*)(ws + (4 << 20) + (1 << 15));            // 32 KB
    float* w1 = (float*)(ws + (4 << 20) + (2 << 15));           // 1 KB
    float* w2 = (float*)(ws + (4 << 20) + (2 << 15) + 4096);    // 1 KB
    unsigned short* wtT = (unsigned short*)(ws + (4 << 20) + (2 << 15) + 8192);  // 256 KB

    hipLaunchKernelGGL(kA, dim3(256), dim3(64), 0, stream, W, a, w1, w2);
    hipLaunchKernelGGL(kA2, dim3(8, 16), dim3(256), 0, stream, wt, wtT);
    hipLaunchKernelGGL(kB, dim3(256), dim3(256), 0, stream, inp, w1, w2, s, t, inpT);
    hipLaunchKernelGGL(kC, dim3(512), dim3(512), 0, stream, adj, s, t, inpT, wtT, out);
}

// Round 7
// 562.019 us; speedup vs baseline: 1.0530x; 1.0339x over previous
//
#include <hip/hip_runtime.h>
#include <stdint.h>

#define GN 8192
#define LOG2E 1.4426950408889634f

typedef float f32x4 __attribute__((ext_vector_type(4)));
typedef short s16x8 __attribute__((ext_vector_type(8)));
typedef unsigned short u16x8 __attribute__((ext_vector_type(8)));
typedef int i32x4 __attribute__((ext_vector_type(4)));

__device__ __forceinline__ unsigned short f2bf(float f) {
    unsigned int u = __float_as_uint(f);
    u += 0x7FFFu + ((u >> 16) & 1u);
    return (unsigned short)(u >> 16);
}
__device__ __forceinline__ float bf2f(unsigned short h) {
    return __uint_as_float(((unsigned int)h) << 16);
}

// w1[k] = log2e * sum_o W[k][o]*a[o];  w2 likewise (pre-scaled for exp2).
__global__ void kA(const float* __restrict__ W, const float* __restrict__ a,
                   float* __restrict__ w1, float* __restrict__ w2) {
    int k = blockIdx.x, l = threadIdx.x;
    float s1 = 0.f, s2 = 0.f;
#pragma unroll
    for (int q = 0; q < 4; ++q) {
        int o = l + q * 64;
        float w = W[k * 256 + o];
        s1 += w * a[o];
        s2 += w * a[256 + o];
    }
#pragma unroll
    for (int off = 32; off; off >>= 1) {
        s1 += __shfl_xor(s1, off);
        s2 += __shfl_xor(s2, off);
    }
    if (l == 0) {
        w1[k] = s1 * LOG2E;
        w2[k] = s2 * LOG2E;
    }
}

// wtT[o][k] = bf16(wtrans[k][o]) via LDS 32x32 tile transpose.
__global__ __launch_bounds__(256) void kA2(const float* __restrict__ wt,
                                           unsigned short* __restrict__ wtT) {
    __shared__ unsigned short Tt[32][33];
    const int bi = blockIdx.x;
    const int bj = blockIdx.y;
    const int ty = threadIdx.x >> 3, tx8 = threadIdx.x & 7;
    float4 v = *(const float4*)(wt + (size_t)(bj * 32 + ty) * 256 + bi * 32 + tx8 * 4);
    Tt[tx8 * 4 + 0][ty] = f2bf(v.x);
    Tt[tx8 * 4 + 1][ty] = f2bf(v.y);
    Tt[tx8 * 4 + 2][ty] = f2bf(v.z);
    Tt[tx8 * 4 + 3][ty] = f2bf(v.w);
    __syncthreads();
    ushort4 o4;
    o4.x = Tt[ty][tx8 * 4 + 0];
    o4.y = Tt[ty][tx8 * 4 + 1];
    o4.z = Tt[ty][tx8 * 4 + 2];
    o4.w = Tt[ty][tx8 * 4 + 3];
    *(ushort4*)(wtT + (size_t)(bi * 32 + ty) * 512 + bj * 32 + tx8 * 4) = o4;
}

// s = inp@w1, t = inp@w2 (pre-scaled), inpT[c][r] = bf16(inp[r][c])
__global__ __launch_bounds__(256) void kB(const float* __restrict__ inp,
                                          const float* __restrict__ w1,
                                          const float* __restrict__ w2,
                                          float* __restrict__ s, float* __restrict__ t,
                                          unsigned short* __restrict__ inpT) {
    __shared__ unsigned short T[256][33];
    const int tid = threadIdx.x;
    const int r0 = blockIdx.x * 32;
    const int r = tid >> 3, cs = tid & 7;
    const float4* in4 = (const float4*)(inp + (size_t)(r0 + r) * 256 + cs * 32);
    const float4* w14 = (const float4*)(w1 + cs * 32);
    const float4* w24 = (const float4*)(w2 + cs * 32);
    float zs = 0.f, zt = 0.f;
#pragma unroll
    for (int q = 0; q < 8; ++q) {
        float4 v = in4[q];
        float4 a1 = w14[q];
        float4 a2 = w24[q];
        zs += v.x * a1.x + v.y * a1.y + v.z * a1.z + v.w * a1.w;
        zt += v.x * a2.x + v.y * a2.y + v.z * a2.z + v.w * a2.w;
        int c = cs * 32 + q * 4;
        T[c + 0][r] = f2bf(v.x);
        T[c + 1][r] = f2bf(v.y);
        T[c + 2][r] = f2bf(v.z);
        T[c + 3][r] = f2bf(v.w);
    }
#pragma unroll
    for (int off = 1; off < 8; off <<= 1) {
        zs += __shfl_xor(zs, off);
        zt += __shfl_xor(zt, off);
    }
    if (cs == 0) {
        s[r0 + r] = zs;
        t[r0 + r] = zt;
    }
    __syncthreads();
    unsigned short* dst = inpT + (size_t)tid * GN + r0;
    ushort4* d4 = (ushort4*)dst;
#pragma unroll
    for (int q = 0; q < 8; ++q) {
        ushort4 v;
        v.x = T[tid][q * 4 + 0];
        v.y = T[tid][q * 4 + 1];
        v.z = T[tid][q * 4 + 2];
        v.w = T[tid][q * 4 + 3];
        d4[q] = v;
    }
}

#define PROCB(Q, TX, BP, BN)                          \
    {                                                 \
        float e = sr + (TX);                          \
        float l = fmaxf(e, 0.2f * e);                 \
        bool on = (m8 & (1u << (Q))) != 0u;           \
        float p1 = on ? exp2f(l) : 0.f;               \
        float p2 = on ? exp2f(-l) : 0.f;              \
        unsigned short b1 = f2bf(p1);                 \
        unsigned short b2 = f2bf(p2);                 \
        zp += bf2f(b1);                               \
        zn += bf2f(b2);                               \
        BP = b1;                                      \
        BN = b2;                                      \
    }

// Fully fused masked double-softmax attention + output GEMM + elu.
// Block: 16 rows x 8192 cols, 512 threads / 8 waves, grid 512.
// LDS layout: P/N in the MFMA-read order [kc][hi][rr][16B] -> both ds_write
// (wave-contiguous 1KB) and ds_read_b128 (lane-contiguous) are conflict-free.
// adj bits cross lane-roles via a packed mask byte in LDS (double-buffered),
// P/N double-buffered -> ONE barrier per iteration (lgkmcnt only).
__global__ __launch_bounds__(512, 2) void kC(const int* __restrict__ adj,
                                             const float* __restrict__ sv,
                                             const float* __restrict__ tv,
                                             const unsigned short* __restrict__ inpT,
                                             const unsigned short* __restrict__ wtT,
                                             float* __restrict__ out) {
    __shared__ __align__(16) char smem[33792];  // P0 P1 [0,16K) N0 N1 [16K,32K) masks [32K,33K)
    __shared__ float Zpart[256];
    __shared__ float Zs[32];
    const int tid = threadIdx.x;
    const int lane = tid & 63, w = tid >> 6;
    const int rr = lane & 15, hi = lane >> 4;
    const int lr = tid >> 5, lc8 = tid & 31;  // adj-loader role
    const int i0 = blockIdx.x * 16;
    const float sr = sv[i0 + rr];  // compute role owns row rr
    float zp = 0.f, zn = 0.f;
    f32x4 accP[2], accN[2];
    accP[0] = (f32x4)(0.f);
    accP[1] = (f32x4)(0.f);
    accN[0] = (f32x4)(0.f);
    accN[1] = (f32x4)(0.f);
    const int fb = w * 32;  // wave's feature slice
    const size_t rowb0 = (size_t)(fb + rr) * GN;
    const size_t rowb1 = (size_t)(fb + 16 + rr) * GN;
    const size_t arowb = (size_t)(i0 + lr) * GN + lc8 * 8;
    const int tspan = w * 32 + hi * 8;
    const int pwoff = w * 1024 + lane * 16;          // P-write offset within buffer
    const int proff = lane * 16;                     // P-read base (+= kc*1024)
    const int moff = 32768;                          // masks base
    const int mrd = rr * 32 + w * 4 + hi;            // mask byte index for compute role

    // prologue: adj chunk 0 -> mask[0]; t chunk 0 -> regs
    {
        i32x4 a0 = *(const i32x4*)(adj + arowb);
        i32x4 a1 = *(const i32x4*)(adj + arowb + 4);
        unsigned nm = (a0.x ? 1u : 0u) | (a0.y ? 2u : 0u) | (a0.z ? 4u : 0u) | (a0.w ? 8u : 0u) |
                      (a1.x ? 16u : 0u) | (a1.y ? 32u : 0u) | (a1.z ? 64u : 0u) | (a1.w ? 128u : 0u);
        *(unsigned char*)(smem + moff + tid) = (unsigned char)nm;
    }
    float4 tf0 = *(const float4*)(tv + tspan);
    float4 tf1 = *(const float4*)(tv + tspan + 4);
    __syncthreads();

    for (int jc = 0; jc < 32; ++jc) {
        const int b8 = (jc & 1) * 8192;
        const size_t jcoff = (size_t)jc * 256;
        float4 tc0 = tf0, tc1 = tf1;
        i32x4 ca0, ca1;
        // prefetch next chunk's adj + t
        if (jc < 31) {
            const int* an = adj + arowb + (jc + 1) * 256;
            ca0 = *(const i32x4*)an;
            ca1 = *(const i32x4*)(an + 4);
            const float* tn = tv + (jc + 1) * 256 + tspan;
            tf0 = *(const float4*)tn;
            tf1 = *(const float4*)(tn + 4);
        }
        // B first half (kc 0..3) -> registers; latency hidden by exp phase
        s16x8 bA[8];
#pragma unroll
        for (int kc = 0; kc < 4; ++kc) {
            bA[kc * 2 + 0] = *(const s16x8*)(inpT + rowb0 + jcoff + kc * 32 + hi * 8);
            bA[kc * 2 + 1] = *(const s16x8*)(inpT + rowb1 + jcoff + kc * 32 + hi * 8);
        }
        __builtin_amdgcn_sched_barrier(0);
        // exp phase: mask byte + t -> 8 p-pairs for (row rr, cols tspan..tspan+8)
        unsigned m8 = (unsigned)*(volatile unsigned char*)(smem + moff + (jc & 1) * 512 + mrd);
        u16x8 up, un;
        PROCB(0, tc0.x, up[0], un[0]);
        PROCB(1, tc0.y, up[1], un[1]);
        PROCB(2, tc0.z, up[2], un[2]);
        PROCB(3, tc0.w, up[3], un[3]);
        PROCB(4, tc1.x, up[4], un[4]);
        PROCB(5, tc1.y, up[5], un[5]);
        PROCB(6, tc1.z, up[6], un[6]);
        PROCB(7, tc1.w, up[7], un[7]);
        *(u16x8*)(smem + b8 + pwoff) = up;
        *(u16x8*)(smem + 16384 + b8 + pwoff) = un;
        // pack next mask (loader role)
        if (jc < 31) {
            unsigned nm = (ca0.x ? 1u : 0u) | (ca0.y ? 2u : 0u) | (ca0.z ? 4u : 0u) | (ca0.w ? 8u : 0u) |
                          (ca1.x ? 16u : 0u) | (ca1.y ? 32u : 0u) | (ca1.z ? 64u : 0u) | (ca1.w ? 128u : 0u);
            *(unsigned char*)(smem + moff + ((jc + 1) & 1) * 512 + tid) = (unsigned char)nm;
        }
        // single barrier: LDS writes visible (no vmcnt drain)
        asm volatile("s_waitcnt lgkmcnt(0)" ::: "memory");
        __builtin_amdgcn_s_barrier();
        asm volatile("" ::: "memory");
        // B second half issued now; latency hidden by first-half MFMAs
        s16x8 bB[8];
#pragma unroll
        for (int kc = 4; kc < 8; ++kc) {
            bB[(kc - 4) * 2 + 0] = *(const s16x8*)(inpT + rowb0 + jcoff + kc * 32 + hi * 8);
            bB[(kc - 4) * 2 + 1] = *(const s16x8*)(inpT + rowb1 + jcoff + kc * 32 + hi * 8);
        }
        __builtin_amdgcn_sched_barrier(0);
#pragma unroll
        for (int kc = 0; kc < 4; ++kc) {
            s16x8 aP = *(const s16x8*)(smem + b8 + kc * 1024 + proff);
            s16x8 aN = *(const s16x8*)(smem + 16384 + b8 + kc * 1024 + proff);
            accP[0] = __builtin_amdgcn_mfma_f32_16x16x32_bf16(aP, bA[kc * 2 + 0], accP[0], 0, 0, 0);
            accP[1] = __builtin_amdgcn_mfma_f32_16x16x32_bf16(aP, bA[kc * 2 + 1], accP[1], 0, 0, 0);
            accN[0] = __builtin_amdgcn_mfma_f32_16x16x32_bf16(aN, bA[kc * 2 + 0], accN[0], 0, 0, 0);
            accN[1] = __builtin_amdgcn_mfma_f32_16x16x32_bf16(aN, bA[kc * 2 + 1], accN[1], 0, 0, 0);
        }
#pragma unroll
        for (int kc = 4; kc < 8; ++kc) {
            s16x8 aP = *(const s16x8*)(smem + b8 + kc * 1024 + proff);
            s16x8 aN = *(const s16x8*)(smem + 16384 + b8 + kc * 1024 + proff);
            accP[0] = __builtin_amdgcn_mfma_f32_16x16x32_bf16(aP, bB[(kc - 4) * 2 + 0], accP[0], 0, 0, 0);
            accP[1] = __builtin_amdgcn_mfma_f32_16x16x32_bf16(aP, bB[(kc - 4) * 2 + 1], accP[1], 0, 0, 0);
            accN[0] = __builtin_amdgcn_mfma_f32_16x16x32_bf16(aN, bB[(kc - 4) * 2 + 0], accN[0], 0, 0, 0);
            accN[1] = __builtin_amdgcn_mfma_f32_16x16x32_bf16(aN, bB[(kc - 4) * 2 + 1], accN[1], 0, 0, 0);
        }
    }
    // Z reduce: sum over hi (lanes xor 16, 32) -> per-wave row partials -> LDS
    zp += __shfl_xor(zp, 16);
    zp += __shfl_xor(zp, 32);
    zn += __shfl_xor(zn, 16);
    zn += __shfl_xor(zn, 32);
    if (lane < 16) {
        Zpart[w * 16 + rr] = zp;
        Zpart[128 + w * 16 + rr] = zn;
    }
    __syncthreads();
    if (tid < 32) {
        int which = tid >> 4, row = tid & 15;
        float z = 0.f;
#pragma unroll
        for (int w2 = 0; w2 < 8; ++w2) z += Zpart[which * 128 + w2 * 16 + row];
        Zs[which * 16 + row] = z;
    }
    __syncthreads();
    // hd tile -> LDS (bf16, swizzled): hd = [num+/Z+, -num-/Z-], [16][512]
    char* hdl = smem;
#pragma unroll
    for (int reg = 0; reg < 4; ++reg) {
        int row = hi * 4 + reg;
        float izp = 1.f / Zs[row];
        float izn = 1.f / Zs[16 + row];
        int sw = (row & 7) << 4;
#pragma unroll
        for (int nt = 0; nt < 2; ++nt) {
            int col = fb + nt * 16 + rr;
            *(unsigned short*)(hdl + ((row * 1024 + col * 2) ^ sw)) =
                f2bf(accP[nt][reg] * izp);
            *(unsigned short*)(hdl + ((row * 1024 + (col + 256) * 2) ^ sw)) =
                f2bf(-accN[nt][reg] * izn);
        }
    }
    __syncthreads();
    // output GEMM: out[16][256] = elu(hdl[16][512] @ wtT^T); wave w -> cols w*32..+31
    f32x4 oc[2];
    oc[0] = (f32x4)(0.f);
    oc[1] = (f32x4)(0.f);
#pragma unroll
    for (int kc = 0; kc < 16; ++kc) {
        int rb = (rr * 1024 + kc * 64 + hi * 16) ^ ((rr & 7) << 4);
        s16x8 av = *(const s16x8*)(hdl + rb);
#pragma unroll
        for (int nt = 0; nt < 2; ++nt) {
            s16x8 b = *(const s16x8*)(wtT + (size_t)(fb + nt * 16 + rr) * 512 + kc * 32 + hi * 8);
            oc[nt] = __builtin_amdgcn_mfma_f32_16x16x32_bf16(av, b, oc[nt], 0, 0, 0);
        }
    }
#pragma unroll
    for (int nt = 0; nt < 2; ++nt) {
        int col = fb + nt * 16 + rr;
#pragma unroll
        for (int reg = 0; reg < 4; ++reg) {
            int row = i0 + hi * 4 + reg;
            float x = oc[nt][reg];
            out[(size_t)row * 256 + col] = x > 0.f ? x : __expf(x) - 1.f;
        }
    }
}

extern "C" void kernel_launch(void* const* d_in, const int* in_sizes, int n_in,
                              void* d_out, int out_size, void* d_ws, size_t ws_size,
                              hipStream_t stream) {
    const float* inp = (const float*)d_in[0];
    const int* adj = (const int*)d_in[1];
    const float* W = (const float*)d_in[2];
    const float* a = (const float*)d_in[3];
    const float* wt = (const float*)d_in[4];
    float* out = (float*)d_out;
    char* ws = (char*)d_ws;

    unsigned short* inpT = (unsigned short*)ws;                 // 4 MB  [256][8192] bf16
    float* s = (float*)(ws + (4 << 20));                        // 32 KB
    float* t = (float*)(ws + (4 << 20) + (1 << 15));            // 32 KB
    float* w1 = (float*)(ws + (4 << 20) + (2 << 15));           // 1 KB
    float* w2 = (float*)(ws + (4 << 20) + (2 << 15) + 4096);    // 1 KB
    unsigned short* wtT = (unsigned short*)(ws + (4 << 20) + (2 << 15) + 8192);  // 256 KB

    hipLaunchKernelGGL(kA, dim3(256), dim3(64), 0, stream, W, a, w1, w2);
    hipLaunchKernelGGL(kA2, dim3(8, 16), dim3(256), 0, stream, wt, wtT);
    hipLaunchKernelGGL(kB, dim3(256), dim3(256), 0, stream, inp, w1, w2, s, t, inpT);
    hipLaunchKernelGGL(kC, dim3(512), dim3(512), 0, stream, adj, s, t, inpT, wtT, out);
}

// Round 8
// 501.334 us; speedup vs baseline: 1.1804x; 1.1210x over previous
//
#include <hip/hip_runtime.h>
#include <stdint.h>

#define GN 8192
#define LOG2E 1.4426950408889634f

typedef float f32x4 __attribute__((ext_vector_type(4)));
typedef short s16x8 __attribute__((ext_vector_type(8)));
typedef unsigned short u16x8 __attribute__((ext_vector_type(8)));
typedef int i32x4 __attribute__((ext_vector_type(4)));

__device__ __forceinline__ unsigned short f2bf(float f) {
    unsigned int u = __float_as_uint(f);
    u += 0x7FFFu + ((u >> 16) & 1u);
    return (unsigned short)(u >> 16);
}
__device__ __forceinline__ float bf2f(unsigned short h) {
    return __uint_as_float(((unsigned int)h) << 16);
}

// w1[k] = log2e * sum_o W[k][o]*a[o];  w2 likewise (pre-scaled for exp2).
__global__ void kA(const float* __restrict__ W, const float* __restrict__ a,
                   float* __restrict__ w1, float* __restrict__ w2) {
    int k = blockIdx.x, l = threadIdx.x;
    float s1 = 0.f, s2 = 0.f;
#pragma unroll
    for (int q = 0; q < 4; ++q) {
        int o = l + q * 64;
        float w = W[k * 256 + o];
        s1 += w * a[o];
        s2 += w * a[256 + o];
    }
#pragma unroll
    for (int off = 32; off; off >>= 1) {
        s1 += __shfl_xor(s1, off);
        s2 += __shfl_xor(s2, off);
    }
    if (l == 0) {
        w1[k] = s1 * LOG2E;
        w2[k] = s2 * LOG2E;
    }
}

// wtT[o][k] = bf16(wtrans[k][o]) via LDS 32x32 tile transpose.
__global__ __launch_bounds__(256) void kA2(const float* __restrict__ wt,
                                           unsigned short* __restrict__ wtT) {
    __shared__ unsigned short Tt[32][33];
    const int bi = blockIdx.x;
    const int bj = blockIdx.y;
    const int ty = threadIdx.x >> 3, tx8 = threadIdx.x & 7;
    float4 v = *(const float4*)(wt + (size_t)(bj * 32 + ty) * 256 + bi * 32 + tx8 * 4);
    Tt[tx8 * 4 + 0][ty] = f2bf(v.x);
    Tt[tx8 * 4 + 1][ty] = f2bf(v.y);
    Tt[tx8 * 4 + 2][ty] = f2bf(v.z);
    Tt[tx8 * 4 + 3][ty] = f2bf(v.w);
    __syncthreads();
    ushort4 o4;
    o4.x = Tt[ty][tx8 * 4 + 0];
    o4.y = Tt[ty][tx8 * 4 + 1];
    o4.z = Tt[ty][tx8 * 4 + 2];
    o4.w = Tt[ty][tx8 * 4 + 3];
    *(ushort4*)(wtT + (size_t)(bi * 32 + ty) * 512 + bj * 32 + tx8 * 4) = o4;
}

// s = inp@w1, t = inp@w2 (pre-scaled), inpT[c][r] = bf16(inp[r][c])
__global__ __launch_bounds__(256) void kB(const float* __restrict__ inp,
                                          const float* __restrict__ w1,
                                          const float* __restrict__ w2,
                                          float* __restrict__ s, float* __restrict__ t,
                                          unsigned short* __restrict__ inpT) {
    __shared__ unsigned short T[256][33];
    const int tid = threadIdx.x;
    const int r0 = blockIdx.x * 32;
    const int r = tid >> 3, cs = tid & 7;
    const float4* in4 = (const float4*)(inp + (size_t)(r0 + r) * 256 + cs * 32);
    const float4* w14 = (const float4*)(w1 + cs * 32);
    const float4* w24 = (const float4*)(w2 + cs * 32);
    float zs = 0.f, zt = 0.f;
#pragma unroll
    for (int q = 0; q < 8; ++q) {
        float4 v = in4[q];
        float4 a1 = w14[q];
        float4 a2 = w24[q];
        zs += v.x * a1.x + v.y * a1.y + v.z * a1.z + v.w * a1.w;
        zt += v.x * a2.x + v.y * a2.y + v.z * a2.z + v.w * a2.w;
        int c = cs * 32 + q * 4;
        T[c + 0][r] = f2bf(v.x);
        T[c + 1][r] = f2bf(v.y);
        T[c + 2][r] = f2bf(v.z);
        T[c + 3][r] = f2bf(v.w);
    }
#pragma unroll
    for (int off = 1; off < 8; off <<= 1) {
        zs += __shfl_xor(zs, off);
        zt += __shfl_xor(zt, off);
    }
    if (cs == 0) {
        s[r0 + r] = zs;
        t[r0 + r] = zt;
    }
    __syncthreads();
    unsigned short* dst = inpT + (size_t)tid * GN + r0;
    ushort4* d4 = (ushort4*)dst;
#pragma unroll
    for (int q = 0; q < 8; ++q) {
        ushort4 v;
        v.x = T[tid][q * 4 + 0];
        v.y = T[tid][q * 4 + 1];
        v.z = T[tid][q * 4 + 2];
        v.w = T[tid][q * 4 + 3];
        d4[q] = v;
    }
}

#define PROCQ(Q, SR, TX, M8, ZP, ZN, BP, BN)          \
    {                                                 \
        float e = (SR) + (TX);                        \
        float l = fmaxf(e, 0.2f * e);                 \
        bool on = ((M8) & (1u << (Q))) != 0u;         \
        float p1 = on ? exp2f(l) : 0.f;               \
        float p2 = on ? exp2f(-l) : 0.f;              \
        unsigned short b1 = f2bf(p1);                 \
        unsigned short b2 = f2bf(p2);                 \
        ZP += bf2f(b1);                               \
        ZN += bf2f(b2);                               \
        BP = b1;                                      \
        BN = b2;                                      \
    }

#define PACK16(A0, A1, A2, A3)                                                          \
    ((unsigned)((A0.x ? 1u : 0u) | (A0.y ? 2u : 0u) | (A0.z ? 4u : 0u) | (A0.w ? 8u : 0u) | \
                (A1.x ? 16u : 0u) | (A1.y ? 32u : 0u) | (A1.z ? 64u : 0u) | (A1.w ? 128u : 0u) | \
                (A2.x ? 256u : 0u) | (A2.y ? 512u : 0u) | (A2.z ? 1024u : 0u) | (A2.w ? 2048u : 0u) | \
                (A3.x ? 4096u : 0u) | (A3.y ? 8192u : 0u) | (A3.z ? 16384u : 0u) | (A3.w ? 32768u : 0u)))

// Fully fused masked double-softmax attention + output GEMM + elu.
// Block: 32 rows x 8192 cols, 512 threads / 8 waves, grid 256 (1 block/CU).
// 2-deep adj pipeline: pack regs loaded 1 iter ago -> mask LDS; conflict-free
// P/N layout [buf][m][kc][wave][lane*16]; masks stride-36; 1 barrier/iter.
__global__ __launch_bounds__(512) void kC(const int* __restrict__ adj,
                                          const float* __restrict__ sv,
                                          const float* __restrict__ tv,
                                          const unsigned short* __restrict__ inpT,
                                          const unsigned short* __restrict__ wtT,
                                          float* __restrict__ out) {
    // P: [0,32K) two bufs; N: [32K,64K); masks: [64K, 64K+2*1152)
    __shared__ __align__(16) char smem[67840];
    __shared__ float Zpart[512];
    __shared__ float Zs[64];
    const int tid = threadIdx.x;
    const int lane = tid & 63, w = tid >> 6;
    const int rr = lane & 15, hi = (lane >> 4) & 3;
    const int lr = tid >> 4, lc = tid & 15;  // adj loader role
    const int i0 = blockIdx.x * 32;
    const float sr0 = sv[i0 + rr];
    const float sr1 = sv[i0 + 16 + rr];
    float zp0 = 0.f, zp1 = 0.f, zn0 = 0.f, zn1 = 0.f;
    f32x4 accP[2][2], accN[2][2];
#pragma unroll
    for (int m = 0; m < 2; ++m)
#pragma unroll
        for (int n = 0; n < 2; ++n) {
            accP[m][n] = (f32x4)(0.f);
            accN[m][n] = (f32x4)(0.f);
        }
    const int fb = w * 32;
    const size_t rowb0 = (size_t)(fb + rr) * GN;
    const size_t rowb1 = (size_t)(fb + 16 + rr) * GN;
    const size_t arowb = (size_t)(i0 + lr) * GN + lc * 16;  // loader base
    const int tspan = w * 32 + hi * 8;
    const int NOFF = 32768, MOFF = 65536;
    const int pw = w * 1024 + lane * 16;         // P/N write offset (m=0)
    const int pr = lane * 16;                    // MFMA read base
    const int mwr = lr * 36 + lc * 2;            // mask write (u16)
    const int mrd0 = rr * 36 + w * 4 + hi;       // mask read row rr
    const int mrd1 = (16 + rr) * 36 + w * 4 + hi;

    // ---- prologue ----
    {   // chunk 0 -> mask[0] directly
        const int* ap = adj + arowb;
        i32x4 a0 = *(const i32x4*)ap;
        i32x4 a1 = *(const i32x4*)(ap + 4);
        i32x4 a2 = *(const i32x4*)(ap + 8);
        i32x4 a3 = *(const i32x4*)(ap + 12);
        *(unsigned short*)(smem + MOFF + mwr) = (unsigned short)PACK16(a0, a1, a2, a3);
    }
    // chunk 1 -> caF regs (issue)
    i32x4 caF0, caF1, caF2, caF3;
    {
        const int* ap = adj + arowb + 256;
        caF0 = *(const i32x4*)ap;
        caF1 = *(const i32x4*)(ap + 4);
        caF2 = *(const i32x4*)(ap + 8);
        caF3 = *(const i32x4*)(ap + 12);
    }
    float4 tf0 = *(const float4*)(tv + tspan);
    float4 tf1 = *(const float4*)(tv + tspan + 4);
    __syncthreads();

    for (int jc = 0; jc < 32; ++jc) {
        const int b16 = (jc & 1) * 16384;
        const size_t jcoff = (size_t)jc * 256;
        float4 tc0 = tf0, tc1 = tf1;
        // B fragments for this chunk -> registers (L2; consumed post-barrier)
        s16x8 bA[8], bB[8];
#pragma unroll
        for (int kc = 0; kc < 4; ++kc) {
            bA[kc * 2 + 0] = *(const s16x8*)(inpT + rowb0 + jcoff + kc * 32 + hi * 8);
            bA[kc * 2 + 1] = *(const s16x8*)(inpT + rowb1 + jcoff + kc * 32 + hi * 8);
        }
#pragma unroll
        for (int kc = 4; kc < 8; ++kc) {
            bB[(kc - 4) * 2 + 0] = *(const s16x8*)(inpT + rowb0 + jcoff + kc * 32 + hi * 8);
            bB[(kc - 4) * 2 + 1] = *(const s16x8*)(inpT + rowb1 + jcoff + kc * 32 + hi * 8);
        }
        // pack adj chunk jc+1 (regs issued 1 iter ago -> latency covered) -> mask LDS
        if (jc < 31) {
            *(unsigned short*)(smem + MOFF + ((jc + 1) & 1) * 1152 + mwr) =
                (unsigned short)PACK16(caF0, caF1, caF2, caF3);
        }
        // issue adj chunk jc+2 (youngest VMEM -> stays in flight across this iter)
        if (jc < 30) {
            const int* ap = adj + arowb + (jc + 2) * 256;
            caF0 = *(const i32x4*)ap;
            caF1 = *(const i32x4*)(ap + 4);
            caF2 = *(const i32x4*)(ap + 8);
            caF3 = *(const i32x4*)(ap + 12);
        }
        if (jc < 31) {
            const float* tn = tv + (jc + 1) * 256 + tspan;
            tf0 = *(const float4*)tn;
            tf1 = *(const float4*)(tn + 4);
        }
        // exp phase: masks (LDS, written last iter) + t regs -> P/N tiles
        unsigned m8a = (unsigned)*(volatile unsigned char*)(smem + MOFF + (jc & 1) * 1152 + mrd0);
        unsigned m8b = (unsigned)*(volatile unsigned char*)(smem + MOFF + (jc & 1) * 1152 + mrd1);
        u16x8 up0, up1, un0, un1;
        PROCQ(0, sr0, tc0.x, m8a, zp0, zn0, up0[0], un0[0]);
        PROCQ(1, sr0, tc0.y, m8a, zp0, zn0, up0[1], un0[1]);
        PROCQ(2, sr0, tc0.z, m8a, zp0, zn0, up0[2], un0[2]);
        PROCQ(3, sr0, tc0.w, m8a, zp0, zn0, up0[3], un0[3]);
        PROCQ(4, sr0, tc1.x, m8a, zp0, zn0, up0[4], un0[4]);
        PROCQ(5, sr0, tc1.y, m8a, zp0, zn0, up0[5], un0[5]);
        PROCQ(6, sr0, tc1.z, m8a, zp0, zn0, up0[6], un0[6]);
        PROCQ(7, sr0, tc1.w, m8a, zp0, zn0, up0[7], un0[7]);
        PROCQ(0, sr1, tc0.x, m8b, zp1, zn1, up1[0], un1[0]);
        PROCQ(1, sr1, tc0.y, m8b, zp1, zn1, up1[1], un1[1]);
        PROCQ(2, sr1, tc0.z, m8b, zp1, zn1, up1[2], un1[2]);
        PROCQ(3, sr1, tc0.w, m8b, zp1, zn1, up1[3], un1[3]);
        PROCQ(4, sr1, tc1.x, m8b, zp1, zn1, up1[4], un1[4]);
        PROCQ(5, sr1, tc1.y, m8b, zp1, zn1, up1[5], un1[5]);
        PROCQ(6, sr1, tc1.z, m8b, zp1, zn1, up1[6], un1[6]);
        PROCQ(7, sr1, tc1.w, m8b, zp1, zn1, up1[7], un1[7]);
        *(u16x8*)(smem + b16 + pw) = up0;
        *(u16x8*)(smem + b16 + 8192 + pw) = up1;
        *(u16x8*)(smem + NOFF + b16 + pw) = un0;
        *(u16x8*)(smem + NOFF + b16 + 8192 + pw) = un1;
        // one barrier: LDS writes visible; VMEM prefetches stay in flight
        asm volatile("s_waitcnt lgkmcnt(0)" ::: "memory");
        __builtin_amdgcn_s_barrier();
        asm volatile("" ::: "memory");
        // MFMA phase
#pragma unroll
        for (int kc = 0; kc < 4; ++kc) {
            s16x8 aP0 = *(const s16x8*)(smem + b16 + kc * 1024 + pr);
            s16x8 aP1 = *(const s16x8*)(smem + b16 + 8192 + kc * 1024 + pr);
            s16x8 aN0 = *(const s16x8*)(smem + NOFF + b16 + kc * 1024 + pr);
            s16x8 aN1 = *(const s16x8*)(smem + NOFF + b16 + 8192 + kc * 1024 + pr);
            s16x8 b0 = bA[kc * 2 + 0], b1 = bA[kc * 2 + 1];
            accP[0][0] = __builtin_amdgcn_mfma_f32_16x16x32_bf16(aP0, b0, accP[0][0], 0, 0, 0);
            accP[0][1] = __builtin_amdgcn_mfma_f32_16x16x32_bf16(aP0, b1, accP[0][1], 0, 0, 0);
            accP[1][0] = __builtin_amdgcn_mfma_f32_16x16x32_bf16(aP1, b0, accP[1][0], 0, 0, 0);
            accP[1][1] = __builtin_amdgcn_mfma_f32_16x16x32_bf16(aP1, b1, accP[1][1], 0, 0, 0);
            accN[0][0] = __builtin_amdgcn_mfma_f32_16x16x32_bf16(aN0, b0, accN[0][0], 0, 0, 0);
            accN[0][1] = __builtin_amdgcn_mfma_f32_16x16x32_bf16(aN0, b1, accN[0][1], 0, 0, 0);
            accN[1][0] = __builtin_amdgcn_mfma_f32_16x16x32_bf16(aN1, b0, accN[1][0], 0, 0, 0);
            accN[1][1] = __builtin_amdgcn_mfma_f32_16x16x32_bf16(aN1, b1, accN[1][1], 0, 0, 0);
        }
#pragma unroll
        for (int kc = 4; kc < 8; ++kc) {
            s16x8 aP0 = *(const s16x8*)(smem + b16 + kc * 1024 + pr);
            s16x8 aP1 = *(const s16x8*)(smem + b16 + 8192 + kc * 1024 + pr);
            s16x8 aN0 = *(const s16x8*)(smem + NOFF + b16 + kc * 1024 + pr);
            s16x8 aN1 = *(const s16x8*)(smem + NOFF + b16 + 8192 + kc * 1024 + pr);
            s16x8 b0 = bB[(kc - 4) * 2 + 0], b1 = bB[(kc - 4) * 2 + 1];
            accP[0][0] = __builtin_amdgcn_mfma_f32_16x16x32_bf16(aP0, b0, accP[0][0], 0, 0, 0);
            accP[0][1] = __builtin_amdgcn_mfma_f32_16x16x32_bf16(aP0, b1, accP[0][1], 0, 0, 0);
            accP[1][0] = __builtin_amdgcn_mfma_f32_16x16x32_bf16(aP1, b0, accP[1][0], 0, 0, 0);
            accP[1][1] = __builtin_amdgcn_mfma_f32_16x16x32_bf16(aP1, b1, accP[1][1], 0, 0, 0);
            accN[0][0] = __builtin_amdgcn_mfma_f32_16x16x32_bf16(aN0, b0, accN[0][0], 0, 0, 0);
            accN[0][1] = __builtin_amdgcn_mfma_f32_16x16x32_bf16(aN0, b1, accN[0][1], 0, 0, 0);
            accN[1][0] = __builtin_amdgcn_mfma_f32_16x16x32_bf16(aN1, b0, accN[1][0], 0, 0, 0);
            accN[1][1] = __builtin_amdgcn_mfma_f32_16x16x32_bf16(aN1, b1, accN[1][1], 0, 0, 0);
        }
    }
    // ---- Z reduction: sum over hi (lane bits 4,5), then across waves ----
    zp0 += __shfl_xor(zp0, 16); zp0 += __shfl_xor(zp0, 32);
    zp1 += __shfl_xor(zp1, 16); zp1 += __shfl_xor(zp1, 32);
    zn0 += __shfl_xor(zn0, 16); zn0 += __shfl_xor(zn0, 32);
    zn1 += __shfl_xor(zn1, 16); zn1 += __shfl_xor(zn1, 32);
    if (lane < 16) {
        Zpart[0 * 128 + w * 16 + rr] = zp0;
        Zpart[1 * 128 + w * 16 + rr] = zp1;
        Zpart[2 * 128 + w * 16 + rr] = zn0;
        Zpart[3 * 128 + w * 16 + rr] = zn1;
    }
    __syncthreads();
    if (tid < 64) {
        int cat = tid >> 4, row = tid & 15;
        float z = 0.f;
#pragma unroll
        for (int wv = 0; wv < 8; ++wv) z += Zpart[cat * 128 + wv * 16 + row];
        // cat0: zp rows 0-15 -> Zs[row]; cat1: zp rows 16-31 -> Zs[16+row]
        // cat2: zn rows 0-15 -> Zs[32+row]; cat3: zn rows 16-31 -> Zs[48+row]
        Zs[(cat & 1) * 16 + (cat >> 1) * 32 + row] = z;
    }
    __syncthreads();
    // ---- hd tile -> LDS (bf16 swizzled [32][512]) ----
    char* hdl = smem;
#pragma unroll
    for (int m = 0; m < 2; ++m)
#pragma unroll
        for (int reg = 0; reg < 4; ++reg) {
            int row = m * 16 + hi * 4 + reg;
            float izp = 1.f / Zs[row];
            float izn = 1.f / Zs[32 + row];
            int sw = (row & 7) << 4;
#pragma unroll
            for (int nt = 0; nt < 2; ++nt) {
                int col = fb + nt * 16 + rr;
                *(unsigned short*)(hdl + ((row * 1024 + col * 2) ^ sw)) =
                    f2bf(accP[m][nt][reg] * izp);
                *(unsigned short*)(hdl + ((row * 1024 + (col + 256) * 2) ^ sw)) =
                    f2bf(-accN[m][nt][reg] * izn);
            }
        }
    __syncthreads();
    // ---- output GEMM: out[32][256] = elu(hdl[32][512] @ wtT^T) ----
    f32x4 oc[2][2];
#pragma unroll
    for (int m = 0; m < 2; ++m)
#pragma unroll
        for (int nt = 0; nt < 2; ++nt) oc[m][nt] = (f32x4)(0.f);
#pragma unroll
    for (int kc = 0; kc < 16; ++kc) {
        int rbs = (rr & 7) << 4;
        s16x8 a0 = *(const s16x8*)(hdl + ((rr * 1024 + kc * 64 + hi * 16) ^ rbs));
        s16x8 a1 = *(const s16x8*)(hdl + (((16 + rr) * 1024 + kc * 64 + hi * 16) ^ rbs));
#pragma unroll
        for (int nt = 0; nt < 2; ++nt) {
            s16x8 b = *(const s16x8*)(wtT + (size_t)(fb + nt * 16 + rr) * 512 + kc * 32 + hi * 8);
            oc[0][nt] = __builtin_amdgcn_mfma_f32_16x16x32_bf16(a0, b, oc[0][nt], 0, 0, 0);
            oc[1][nt] = __builtin_amdgcn_mfma_f32_16x16x32_bf16(a1, b, oc[1][nt], 0, 0, 0);
        }
    }
#pragma unroll
    for (int m = 0; m < 2; ++m)
#pragma unroll
        for (int nt = 0; nt < 2; ++nt) {
            int col = fb + nt * 16 + rr;
#pragma unroll
            for (int reg = 0; reg < 4; ++reg) {
                int row = i0 + m * 16 + hi * 4 + reg;
                float x = oc[m][nt][reg];
                out[(size_t)row * 256 + col] = x > 0.f ? x : __expf(x) - 1.f;
            }
        }
}

extern "C" void kernel_launch(void* const* d_in, const int* in_sizes, int n_in,
                              void* d_out, int out_size, void* d_ws, size_t ws_size,
                              hipStream_t stream) {
    const float* inp = (const float*)d_in[0];
    const int* adj = (const int*)d_in[1];
    const float* W = (const float*)d_in[2];
    const float* a = (const float*)d_in[3];
    const float* wt = (const float*)d_in[4];
    float* out = (float*)d_out;
    char* ws = (char*)d_ws;

    unsigned short* inpT = (unsigned short*)ws;                 // 4 MB  [256][8192] bf16
    float* s = (float*)(ws + (4 << 20));                        // 32 KB
    float* t = (float*)(ws + (4 << 20) + (1 << 15));            // 32 KB
    float* w1 = (float*)(ws + (4 << 20) + (2 << 15));           // 1 KB
    float* w2 = (float*)(ws + (4 << 20) + (2 << 15) + 4096);    // 1 KB
    unsigned short* wtT = (unsigned short*)(ws + (4 << 20) + (2 << 15) + 8192);  // 256 KB

    hipLaunchKernelGGL(kA, dim3(256), dim3(64), 0, stream, W, a, w1, w2);
    hipLaunchKernelGGL(kA2, dim3(8, 16), dim3(256), 0, stream, wt, wtT);
    hipLaunchKernelGGL(kB, dim3(256), dim3(256), 0, stream, inp, w1, w2, s, t, inpT);
    hipLaunchKernelGGL(kC, dim3(256), dim3(512), 0, stream, adj, s, t, inpT, wtT, out);
}